// Round 1
// baseline (1867.827 us; speedup 1.0000x reference)
//
#include <hip/hip_runtime.h>

#define F_IN 128
#define HH1 128
#define HH2 64
#define FOUT 50

// ---- edge dtype detection (int64 vs int32) ---------------------------------
__global__ void detect_kernel(const unsigned int* __restrict__ raw, int* __restrict__ flag) {
    __shared__ int nonzero;
    if (threadIdx.x == 0) nonzero = 0;
    __syncthreads();
    // If buffer is int64 little-endian with values < 2^31, odd words are all 0.
    if (raw[2 * threadIdx.x + 1] != 0u) atomicOr(&nonzero, 1);
    __syncthreads();
    if (threadIdx.x == 0) *flag = (nonzero ? 0 : 1);  // 1 => int64
}

__global__ void convert_edges(const int* __restrict__ raw, const int* __restrict__ flag,
                              int* __restrict__ out, int n) {
    int tid = blockIdx.x * 256 + threadIdx.x;
    if (tid >= n) return;
    int is64 = *flag;
    out[tid] = is64 ? raw[2 * tid] : raw[tid];
}

// ---- degree / dinv ----------------------------------------------------------
__global__ void init_deg(float* __restrict__ deg, int n) {
    int i = blockIdx.x * 256 + threadIdx.x;
    if (i < n) deg[i] = 1.0f;  // self-loop
}

__global__ void count_deg(const int* __restrict__ dst, float* __restrict__ deg, int E) {
    int e = blockIdx.x * 256 + threadIdx.x;
    if (e < E) atomicAdd(&deg[dst[e]], 1.0f);
}

__global__ void make_dinv(const float* __restrict__ deg, float* __restrict__ dinv, int n) {
    int i = blockIdx.x * 256 + threadIdx.x;
    if (i < n) dinv[i] = rsqrtf(deg[i]);  // deg >= 1 always (self-loops)
}

// ---- small fp32 GEMM: Y[M,NC] = (relu?)X[M,K] @ W[K,NC] (+bias) -------------
// 8 rows/block, 32 threads/row, NPT columns per thread strided by 32.
template <int K, int NC, int NPT, bool RELU_IN, bool BIAS>
__global__ __launch_bounds__(256) void gemm_kernel(const float* __restrict__ X,
                                                   const float* __restrict__ W,
                                                   const float* __restrict__ bias,
                                                   float* __restrict__ Y, int M) {
    __shared__ float ws[32 * NC];  // K-tile of W
    __shared__ float xs[256];      // 8 rows x 32 k
    const int tid = threadIdx.x;
    const int rlocal = tid >> 5;
    const int cbase = tid & 31;
    const int row = blockIdx.x * 8 + rlocal;
    float acc[NPT];
#pragma unroll
    for (int j = 0; j < NPT; ++j) acc[j] = 0.f;

    for (int kk = 0; kk < K; kk += 32) {
        for (int idx = tid; idx < 32 * NC; idx += 256) ws[idx] = W[kk * NC + idx];
        {
            float v = 0.f;
            if (row < M) v = X[(long)row * K + kk + cbase];
            if (RELU_IN) v = fmaxf(v, 0.f);
            xs[tid] = v;
        }
        __syncthreads();
#pragma unroll
        for (int k = 0; k < 32; ++k) {
            float xv = xs[(rlocal << 5) + k];
#pragma unroll
            for (int j = 0; j < NPT; ++j) {
                int c = cbase + 32 * j;
                if (NC % 32 == 0 || c < NC) acc[j] = fmaf(xv, ws[k * NC + c], acc[j]);
            }
        }
        __syncthreads();
    }
    if (row < M) {
#pragma unroll
        for (int j = 0; j < NPT; ++j) {
            int c = cbase + 32 * j;
            if (NC % 32 == 0 || c < NC) {
                float v = acc[j];
                if (BIAS) v += bias[c];
                Y[(long)row * NC + c] = v;
            }
        }
    }
}

// ---- aggregation ------------------------------------------------------------
// agg[i] = bias + dinv[i]^2 * h[i]   (self-loop term, write-once)
template <int F4>
__global__ void agg_init_kernel(const float* __restrict__ h, const float* __restrict__ dinv,
                                const float* __restrict__ bias, float* __restrict__ agg, int n) {
    int tid = blockIdx.x * 256 + threadIdx.x;
    if (tid >= n * F4) return;
    int i = tid / F4;
    int c4 = tid - i * F4;
    float di = dinv[i];
    float coef = di * di;
    float4 hv = ((const float4*)h)[tid];
    float4 bv = ((const float4*)bias)[c4];
    float4 o;
    o.x = fmaf(coef, hv.x, bv.x);
    o.y = fmaf(coef, hv.y, bv.y);
    o.z = fmaf(coef, hv.z, bv.z);
    o.w = fmaf(coef, hv.w, bv.w);
    ((float4*)agg)[tid] = o;
}

// agg[dst] += dinv[src]*dinv[dst] * h[src]   (atomics)
template <int F4>
__global__ void agg_edge_kernel(const float* __restrict__ h, const int* __restrict__ src,
                                const int* __restrict__ dst, const float* __restrict__ dinv,
                                float* __restrict__ agg, int E) {
    int tid = blockIdx.x * 256 + threadIdx.x;
    if (tid >= E * F4) return;
    int e = tid / F4;
    int c4 = tid - e * F4;
    int s = src[e];
    int d = dst[e];
    float coef = dinv[s] * dinv[d];
    float4 v = ((const float4*)h)[(long)s * F4 + c4];
    float* o = agg + ((long)d * F4 + c4) * 4;
    atomicAdd(o + 0, coef * v.x);
    atomicAdd(o + 1, coef * v.y);
    atomicAdd(o + 2, coef * v.z);
    atomicAdd(o + 3, coef * v.w);
}

// ---- launch -----------------------------------------------------------------
extern "C" void kernel_launch(void* const* d_in, const int* in_sizes, int n_in,
                              void* d_out, int out_size, void* d_ws, size_t ws_size,
                              hipStream_t stream) {
    const float* x   = (const float*)d_in[0];
    const int*   eraw= (const int*)d_in[1];
    const float* W1  = (const float*)d_in[2];
    const float* b1  = (const float*)d_in[3];
    const float* W2  = (const float*)d_in[4];
    const float* b2  = (const float*)d_in[5];
    const float* Wh  = (const float*)d_in[6];
    const float* bh  = (const float*)d_in[7];
    float* out = (float*)d_out;
    const int n = in_sizes[0] / F_IN;
    const int E = in_sizes[1] / 2;

    char* p = (char*)d_ws;
    int* flag   = (int*)p;   p += 256;
    int* edges  = (int*)p;   p += (size_t)2 * E * sizeof(int);
    float* deg  = (float*)p; p += (size_t)n * sizeof(float);
    float* dinv = (float*)p; p += (size_t)n * sizeof(float);
    float* bufA = (float*)p; p += (size_t)n * HH1 * sizeof(float);
    float* bufB = (float*)p;                    // n*HH1 floats
    const int* src = edges;
    const int* dst = edges + E;
    float* h1 = bufA;
    float* agg1 = bufB;
    float* h2 = bufA;                           // h1 dead by then
    float* agg2 = bufA + (size_t)n * HH2;       // disjoint from h2

    dim3 blk(256);
    detect_kernel<<<1, 256, 0, stream>>>((const unsigned int*)eraw, flag);
    convert_edges<<<(2 * E + 255) / 256, blk, 0, stream>>>(eraw, flag, edges, 2 * E);
    init_deg<<<(n + 255) / 256, blk, 0, stream>>>(deg, n);
    count_deg<<<(E + 255) / 256, blk, 0, stream>>>(dst, deg, E);
    make_dinv<<<(n + 255) / 256, blk, 0, stream>>>(deg, dinv, n);

    const int gblocks = (n + 7) / 8;
    // layer 1
    gemm_kernel<F_IN, HH1, 4, false, false><<<gblocks, blk, 0, stream>>>(x, W1, nullptr, h1, n);
    agg_init_kernel<HH1 / 4><<<(n * (HH1 / 4) + 255) / 256, blk, 0, stream>>>(h1, dinv, b1, agg1, n);
    agg_edge_kernel<HH1 / 4><<<(E * (HH1 / 4) + 255) / 256, blk, 0, stream>>>(h1, src, dst, dinv, agg1, E);
    // layer 2
    gemm_kernel<HH1, HH2, 2, true, false><<<gblocks, blk, 0, stream>>>(agg1, W2, nullptr, h2, n);
    agg_init_kernel<HH2 / 4><<<(n * (HH2 / 4) + 255) / 256, blk, 0, stream>>>(h2, dinv, b2, agg2, n);
    agg_edge_kernel<HH2 / 4><<<(E * (HH2 / 4) + 255) / 256, blk, 0, stream>>>(h2, src, dst, dinv, agg2, E);
    // head
    gemm_kernel<HH2, FOUT, 2, true, true><<<gblocks, blk, 0, stream>>>(agg2, Wh, bh, out, n);
}

// Round 2
// 412.942 us; speedup vs baseline: 4.5232x; 4.5232x over previous
//
#include <hip/hip_runtime.h>

#define F_IN 128
#define HH1 128
#define HH2 64
#define FOUT 50

// ---- edge dtype detection (int64 vs int32) ---------------------------------
__global__ void detect_kernel(const unsigned int* __restrict__ raw, int* __restrict__ flag) {
    __shared__ int nonzero;
    if (threadIdx.x == 0) nonzero = 0;
    __syncthreads();
    if (raw[2 * threadIdx.x + 1] != 0u) atomicOr(&nonzero, 1);
    __syncthreads();
    if (threadIdx.x == 0) *flag = (nonzero ? 0 : 1);  // 1 => int64
}

__global__ void convert_edges(const int* __restrict__ raw, const int* __restrict__ flag,
                              int* __restrict__ out, int n) {
    int tid = blockIdx.x * 256 + threadIdx.x;
    if (tid >= n) return;
    int is64 = *flag;
    out[tid] = is64 ? raw[2 * tid] : raw[tid];
}

// ---- degree / dinv ----------------------------------------------------------
__global__ void init_deg(int* __restrict__ deg, int n) {
    int i = blockIdx.x * 256 + threadIdx.x;
    if (i < n) deg[i] = 0;
}

__global__ void count_deg(const int* __restrict__ dst, int* __restrict__ deg, int E) {
    int e = blockIdx.x * 256 + threadIdx.x;
    if (e < E) atomicAdd(&deg[dst[e]], 1);
}

__global__ void make_dinv(const int* __restrict__ deg, float* __restrict__ dinv, int n) {
    int i = blockIdx.x * 256 + threadIdx.x;
    if (i < n) dinv[i] = rsqrtf((float)deg[i] + 1.0f);  // +1 self-loop
}

// ---- exclusive scan (3 kernels, n <= 256*256) -------------------------------
__global__ void scan_block(const int* __restrict__ deg, int* __restrict__ excl,
                           int* __restrict__ bsums, int n) {
    __shared__ int sh[256];
    int tid = threadIdx.x;
    int gid = blockIdx.x * 256 + tid;
    int v = (gid < n) ? deg[gid] : 0;
    sh[tid] = v;
    __syncthreads();
    for (int off = 1; off < 256; off <<= 1) {
        int t = (tid >= off) ? sh[tid - off] : 0;
        __syncthreads();
        sh[tid] += t;
        __syncthreads();
    }
    if (gid < n) excl[gid] = sh[tid] - v;
    if (tid == 255) bsums[blockIdx.x] = sh[255];
}

__global__ void scan_tops(int* __restrict__ bsums, int nb) {
    __shared__ int sh[256];
    int tid = threadIdx.x;
    int v = (tid < nb) ? bsums[tid] : 0;
    sh[tid] = v;
    __syncthreads();
    for (int off = 1; off < 256; off <<= 1) {
        int t = (tid >= off) ? sh[tid - off] : 0;
        __syncthreads();
        sh[tid] += t;
        __syncthreads();
    }
    if (tid < nb) bsums[tid] = sh[tid] - v;  // exclusive
}

__global__ void scan_add(int* __restrict__ rowptr, const int* __restrict__ bsums,
                         int* __restrict__ cursor, int n, int E) {
    int gid = blockIdx.x * 256 + threadIdx.x;
    if (gid < n) {
        int v = rowptr[gid] + bsums[gid >> 8];
        rowptr[gid] = v;
        cursor[gid] = v;
    }
    if (gid == 0) rowptr[n] = E;
}

// ---- CSR scatter (dst-bucketed), precompute per-edge coef -------------------
__global__ void scatter_edges(const int* __restrict__ src, const int* __restrict__ dst,
                              const float* __restrict__ dinv, int* __restrict__ cursor,
                              int* __restrict__ csr_src, float* __restrict__ csr_coef, int E) {
    int e = blockIdx.x * 256 + threadIdx.x;
    if (e >= E) return;
    int s = src[e];
    int d = dst[e];
    int pos = atomicAdd(&cursor[d], 1);
    csr_src[pos] = s;
    csr_coef[pos] = dinv[s] * dinv[d];
}

// ---- small fp32 GEMM: Y[M,NC] = (relu?)X[M,K] @ W[K,NC] (+bias) -------------
template <int K, int NC, int NPT, bool RELU_IN, bool BIAS>
__global__ __launch_bounds__(256) void gemm_kernel(const float* __restrict__ X,
                                                   const float* __restrict__ W,
                                                   const float* __restrict__ bias,
                                                   float* __restrict__ Y, int M) {
    __shared__ float ws[32 * NC];
    __shared__ float xs[256];
    const int tid = threadIdx.x;
    const int rlocal = tid >> 5;
    const int cbase = tid & 31;
    const int row = blockIdx.x * 8 + rlocal;
    float acc[NPT];
#pragma unroll
    for (int j = 0; j < NPT; ++j) acc[j] = 0.f;

    for (int kk = 0; kk < K; kk += 32) {
        for (int idx = tid; idx < 32 * NC; idx += 256) ws[idx] = W[kk * NC + idx];
        {
            float v = 0.f;
            if (row < M) v = X[(long)row * K + kk + cbase];
            if (RELU_IN) v = fmaxf(v, 0.f);
            xs[tid] = v;
        }
        __syncthreads();
#pragma unroll
        for (int k = 0; k < 32; ++k) {
            float xv = xs[(rlocal << 5) + k];
#pragma unroll
            for (int j = 0; j < NPT; ++j) {
                int c = cbase + 32 * j;
                if (NC % 32 == 0 || c < NC) acc[j] = fmaf(xv, ws[k * NC + c], acc[j]);
            }
        }
        __syncthreads();
    }
    if (row < M) {
#pragma unroll
        for (int j = 0; j < NPT; ++j) {
            int c = cbase + 32 * j;
            if (NC % 32 == 0 || c < NC) {
                float v = acc[j];
                if (BIAS) v += bias[c];
                Y[(long)row * NC + c] = v;
            }
        }
    }
}

// ---- CSR aggregation: agg[i] = bias + dinv[i]^2*h[i] + sum_e coef*h[src] ----
// LPN lanes per node, float4 per lane; one coalesced write per node, no atomics.
template <int LPN, int NPB>
__global__ __launch_bounds__(256) void agg_csr_kernel(const float* __restrict__ h,
                                                      const int* __restrict__ rowptr,
                                                      const int* __restrict__ csr_src,
                                                      const float* __restrict__ csr_coef,
                                                      const float* __restrict__ dinv,
                                                      const float* __restrict__ bias,
                                                      float* __restrict__ agg, int n) {
    const int tid = threadIdx.x;
    const int node = blockIdx.x * NPB + tid / LPN;
    const int lane = tid % LPN;
    if (node >= n) return;
    const float4* __restrict__ h4 = (const float4*)h;

    float4 acc = ((const float4*)bias)[lane];
    float di = dinv[node];
    float cs = di * di;
    float4 hv = h4[(long)node * LPN + lane];
    acc.x = fmaf(cs, hv.x, acc.x);
    acc.y = fmaf(cs, hv.y, acc.y);
    acc.z = fmaf(cs, hv.z, acc.z);
    acc.w = fmaf(cs, hv.w, acc.w);

    int e = rowptr[node];
    const int end = rowptr[node + 1];
    for (; e + 1 < end; e += 2) {
        int s0 = csr_src[e];
        int s1 = csr_src[e + 1];
        float c0 = csr_coef[e];
        float c1 = csr_coef[e + 1];
        float4 v0 = h4[(long)s0 * LPN + lane];
        float4 v1 = h4[(long)s1 * LPN + lane];
        acc.x = fmaf(c0, v0.x, acc.x);
        acc.y = fmaf(c0, v0.y, acc.y);
        acc.z = fmaf(c0, v0.z, acc.z);
        acc.w = fmaf(c0, v0.w, acc.w);
        acc.x = fmaf(c1, v1.x, acc.x);
        acc.y = fmaf(c1, v1.y, acc.y);
        acc.z = fmaf(c1, v1.z, acc.z);
        acc.w = fmaf(c1, v1.w, acc.w);
    }
    if (e < end) {
        int s0 = csr_src[e];
        float c0 = csr_coef[e];
        float4 v0 = h4[(long)s0 * LPN + lane];
        acc.x = fmaf(c0, v0.x, acc.x);
        acc.y = fmaf(c0, v0.y, acc.y);
        acc.z = fmaf(c0, v0.z, acc.z);
        acc.w = fmaf(c0, v0.w, acc.w);
    }
    ((float4*)agg)[(long)node * LPN + lane] = acc;
}

// ---- launch -----------------------------------------------------------------
extern "C" void kernel_launch(void* const* d_in, const int* in_sizes, int n_in,
                              void* d_out, int out_size, void* d_ws, size_t ws_size,
                              hipStream_t stream) {
    const float* x    = (const float*)d_in[0];
    const int*   eraw = (const int*)d_in[1];
    const float* W1   = (const float*)d_in[2];
    const float* b1   = (const float*)d_in[3];
    const float* W2   = (const float*)d_in[4];
    const float* b2   = (const float*)d_in[5];
    const float* Wh   = (const float*)d_in[6];
    const float* bh   = (const float*)d_in[7];
    float* out = (float*)d_out;
    const int n = in_sizes[0] / F_IN;
    const int E = in_sizes[1] / 2;
    const int nb = (n + 255) / 256;

    // ---- workspace layout (overlays; total ~57 MB) ----
    char* p = (char*)d_ws;
    int*   flag     = (int*)p;   p += 256;
    float* dinv     = (float*)p; p += (size_t)n * sizeof(float);
    int*   rowptr   = (int*)p;   p += (size_t)(n + 1) * sizeof(int);
    int*   bsums    = (int*)p;   p += 4096;
    int*   csr_src  = (int*)p;   p += (size_t)E * sizeof(int);
    float* csr_coef = (float*)p; p += (size_t)E * sizeof(float);
    int*   degcur   = (int*)p;   p += (size_t)n * sizeof(int);   // deg, then cursor
    float* bigA     = (float*)p; p += (size_t)n * HH1 * sizeof(float);
    float* bigB     = (float*)p;
    // edges overlay the start of bigA (dead before GEMM1 writes h1 there)
    int* edges = (int*)bigA;
    const int* srcv = edges;
    const int* dstv = edges + E;
    float* h1   = bigA;
    float* agg1 = bigB;
    float* h2   = bigA;                      // 12.8 MB
    float* agg2 = bigA + (size_t)n * HH2;    // disjoint from h2
    int* deg = degcur;
    int* cursor = degcur;

    dim3 blk(256);
    // graph prep
    detect_kernel<<<1, 256, 0, stream>>>((const unsigned int*)eraw, flag);
    convert_edges<<<(2 * E + 255) / 256, blk, 0, stream>>>(eraw, flag, edges, 2 * E);
    init_deg<<<nb, blk, 0, stream>>>(deg, n);
    count_deg<<<(E + 255) / 256, blk, 0, stream>>>(dstv, deg, E);
    make_dinv<<<nb, blk, 0, stream>>>(deg, dinv, n);
    scan_block<<<nb, blk, 0, stream>>>(deg, rowptr, bsums, n);
    scan_tops<<<1, blk, 0, stream>>>(bsums, nb);
    scan_add<<<nb, blk, 0, stream>>>(rowptr, bsums, cursor, n, E);
    scatter_edges<<<(E + 255) / 256, blk, 0, stream>>>(srcv, dstv, dinv, cursor, csr_src, csr_coef, E);

    const int gblocks = (n + 7) / 8;
    // layer 1
    gemm_kernel<F_IN, HH1, 4, false, false><<<gblocks, blk, 0, stream>>>(x, W1, nullptr, h1, n);
    agg_csr_kernel<32, 8><<<(n + 7) / 8, blk, 0, stream>>>(h1, rowptr, csr_src, csr_coef, dinv, b1, agg1, n);
    // layer 2
    gemm_kernel<HH1, HH2, 2, true, false><<<gblocks, blk, 0, stream>>>(agg1, W2, nullptr, h2, n);
    agg_csr_kernel<16, 16><<<(n + 15) / 16, blk, 0, stream>>>(h2, rowptr, csr_src, csr_coef, dinv, b2, agg2, n);
    // head
    gemm_kernel<HH2, FOUT, 2, true, true><<<gblocks, blk, 0, stream>>>(agg2, Wh, bh, out, n);
}

// Round 3
// 195.358 us; speedup vs baseline: 9.5610x; 2.1138x over previous
//
#include <hip/hip_runtime.h>

#define F_IN 128
#define HH1 128
#define HH2 64
#define FOUT 50

typedef __attribute__((ext_vector_type(8))) short short8;
typedef __attribute__((ext_vector_type(4))) short s16x4;
typedef __attribute__((ext_vector_type(4))) float f32x4;

__device__ inline short f2bf(float f) {  // RNE fp32->bf16
    union { float f; unsigned u; } v; v.f = f;
    unsigned r = v.u + 0x7fffu + ((v.u >> 16) & 1u);
    return (short)(r >> 16);
}
__device__ inline float bf2f(short s) {
    union { float f; unsigned u; } v; v.u = ((unsigned)(unsigned short)s) << 16;
    return v.f;
}

// ---- edge dtype detection (int64 vs int32) ---------------------------------
__global__ void detect_kernel(const unsigned int* __restrict__ raw, int* __restrict__ flag) {
    __shared__ int nonzero;
    if (threadIdx.x == 0) nonzero = 0;
    __syncthreads();
    if (raw[2 * threadIdx.x + 1] != 0u) atomicOr(&nonzero, 1);
    __syncthreads();
    if (threadIdx.x == 0) *flag = (nonzero ? 0 : 1);  // 1 => int64
}

__global__ void convert_edges(const int* __restrict__ raw, const int* __restrict__ flag,
                              int* __restrict__ out, int n) {
    int tid = blockIdx.x * 256 + threadIdx.x;
    if (tid >= n) return;
    int is64 = *flag;
    out[tid] = is64 ? raw[2 * tid] : raw[tid];
}

// ---- degree / dinv ----------------------------------------------------------
__global__ void init_deg(int* __restrict__ deg, int n) {
    int i = blockIdx.x * 256 + threadIdx.x;
    if (i < n) deg[i] = 0;
}
__global__ void count_deg(const int* __restrict__ dst, int* __restrict__ deg, int E) {
    int e = blockIdx.x * 256 + threadIdx.x;
    if (e < E) atomicAdd(&deg[dst[e]], 1);
}
__global__ void make_dinv(const int* __restrict__ deg, float* __restrict__ dinv, int n) {
    int i = blockIdx.x * 256 + threadIdx.x;
    if (i < n) dinv[i] = rsqrtf((float)deg[i] + 1.0f);  // +1 self-loop
}

// ---- exclusive scan (3 kernels, n <= 256*256) -------------------------------
__global__ void scan_block(const int* __restrict__ deg, int* __restrict__ excl,
                           int* __restrict__ bsums, int n) {
    __shared__ int sh[256];
    int tid = threadIdx.x;
    int gid = blockIdx.x * 256 + tid;
    int v = (gid < n) ? deg[gid] : 0;
    sh[tid] = v;
    __syncthreads();
    for (int off = 1; off < 256; off <<= 1) {
        int t = (tid >= off) ? sh[tid - off] : 0;
        __syncthreads();
        sh[tid] += t;
        __syncthreads();
    }
    if (gid < n) excl[gid] = sh[tid] - v;
    if (tid == 255) bsums[blockIdx.x] = sh[255];
}
__global__ void scan_tops(int* __restrict__ bsums, int nb) {
    __shared__ int sh[256];
    int tid = threadIdx.x;
    int v = (tid < nb) ? bsums[tid] : 0;
    sh[tid] = v;
    __syncthreads();
    for (int off = 1; off < 256; off <<= 1) {
        int t = (tid >= off) ? sh[tid - off] : 0;
        __syncthreads();
        sh[tid] += t;
        __syncthreads();
    }
    if (tid < nb) bsums[tid] = sh[tid] - v;  // exclusive
}
__global__ void scan_add(int* __restrict__ rowptr, const int* __restrict__ bsums,
                         int* __restrict__ cursor, int n, int E) {
    int gid = blockIdx.x * 256 + threadIdx.x;
    if (gid < n) {
        int v = rowptr[gid] + bsums[gid >> 8];
        rowptr[gid] = v;
        cursor[gid] = v;
    }
    if (gid == 0) rowptr[n] = E;
}

// ---- CSR scatter (dst-bucketed), precompute per-edge coef -------------------
__global__ void scatter_edges(const int* __restrict__ src, const int* __restrict__ dst,
                              const float* __restrict__ dinv, int* __restrict__ cursor,
                              int* __restrict__ csr_src, float* __restrict__ csr_coef, int E) {
    int e = blockIdx.x * 256 + threadIdx.x;
    if (e >= E) return;
    int s = src[e];
    int d = dst[e];
    int pos = atomicAdd(&cursor[d], 1);
    csr_src[pos] = s;
    csr_coef[pos] = dinv[s] * dinv[d];
}

// ---- weight transpose to bf16: Wt[c][k] = bf16(W[k][c]), c>=NC -> 0 ---------
__global__ void wtrans(const float* __restrict__ W, short* __restrict__ Wt,
                       int K, int NC, int NCP) {
    int idx = blockIdx.x * 256 + threadIdx.x;
    if (idx >= NCP * K) return;
    int c = idx / K;
    int k = idx - c * K;
    float v = (c < NC) ? W[(long)k * NC + c] : 0.f;
    Wt[idx] = f2bf(v);
}

// ---- MFMA GEMM: Y[M,NC] = X[M,K] @ Wt^T, per-wave 16-row tile ---------------
// A-frag: row=lane&15, k=(lane>>4)*8+j (8 contiguous bf16).
// B-frag: col=lane&15, same k layout (Wt stored [NC][K]).
// C/D:    col=lane&15, row=(lane>>4)*4+j.
template <int K, int NC, bool IN_BF16, bool OUT_F32, bool BIAS>
__global__ __launch_bounds__(256) void mfma_gemm(const void* __restrict__ Xv,
                                                 const short* __restrict__ Wt,
                                                 const float* __restrict__ bias,
                                                 void* __restrict__ Yv, int M, int NCOUT) {
    const int tid = threadIdx.x;
    const int wave = tid >> 6;
    const int lane = tid & 63;
    const int l15 = lane & 15;
    const int kg = lane >> 4;
    const int rowbase = blockIdx.x * 64 + wave * 16;
    const int arow = rowbase + l15;
    constexpr int KS = K / 32;

    short8 af[KS];
    if (arow < M) {
        if (IN_BF16) {
            const short* xr = (const short*)Xv + (long)arow * K + kg * 8;
#pragma unroll
            for (int ks = 0; ks < KS; ++ks) af[ks] = *(const short8*)(xr + ks * 32);
        } else {
            const float* xr = (const float*)Xv + (long)arow * K + kg * 8;
#pragma unroll
            for (int ks = 0; ks < KS; ++ks) {
                float4 f0 = *(const float4*)(xr + ks * 32);
                float4 f1 = *(const float4*)(xr + ks * 32 + 4);
                short8 a;
                a[0] = f2bf(f0.x); a[1] = f2bf(f0.y); a[2] = f2bf(f0.z); a[3] = f2bf(f0.w);
                a[4] = f2bf(f1.x); a[5] = f2bf(f1.y); a[6] = f2bf(f1.z); a[7] = f2bf(f1.w);
                af[ks] = a;
            }
        }
    } else {
#pragma unroll
        for (int ks = 0; ks < KS; ++ks) af[ks] = (short8)0;
    }

    const int crowb = rowbase + kg * 4;
#pragma unroll
    for (int ct = 0; ct < NC / 16; ++ct) {
        const int col = ct * 16 + l15;
        const short* wr = Wt + (long)col * K + kg * 8;
        f32x4 acc = {0.f, 0.f, 0.f, 0.f};
#pragma unroll
        for (int ks = 0; ks < KS; ++ks) {
            short8 bf = *(const short8*)(wr + ks * 32);
            acc = __builtin_amdgcn_mfma_f32_16x16x32_bf16(af[ks], bf, acc, 0, 0, 0);
        }
        if (OUT_F32) {
            float* Y = (float*)Yv;
            float bv = BIAS ? bias[col] : 0.f;
#pragma unroll
            for (int j = 0; j < 4; ++j) {
                int r = crowb + j;
                if (r < M && col < NCOUT) Y[(long)r * NCOUT + col] = acc[j] + bv;
            }
        } else {
            short* Y = (short*)Yv;
#pragma unroll
            for (int j = 0; j < 4; ++j) {
                int r = crowb + j;
                if (r < M) Y[(long)r * NC + col] = f2bf(acc[j]);
            }
        }
    }
}

// ---- CSR aggregation, bf16 features -----------------------------------------
// agg[i] = relu(bias + dinv[i]^2*h[i] + sum_e coef*h[src]) -> bf16
template <int LPN, int NPB>
__global__ __launch_bounds__(256) void agg_csr_bf16(const short* __restrict__ h,
                                                    const int* __restrict__ rowptr,
                                                    const int* __restrict__ csr_src,
                                                    const float* __restrict__ csr_coef,
                                                    const float* __restrict__ dinv,
                                                    const float* __restrict__ bias,
                                                    short* __restrict__ agg, int n) {
    const int tid = threadIdx.x;
    const int node = blockIdx.x * NPB + tid / LPN;
    const int lane = tid % LPN;
    if (node >= n) return;
    const s16x4* __restrict__ h4 = (const s16x4*)h;

    float4 acc = ((const float4*)bias)[lane];
    float di = dinv[node];
    float cs = di * di;
    s16x4 hv = h4[(long)node * LPN + lane];
    acc.x = fmaf(cs, bf2f(hv[0]), acc.x);
    acc.y = fmaf(cs, bf2f(hv[1]), acc.y);
    acc.z = fmaf(cs, bf2f(hv[2]), acc.z);
    acc.w = fmaf(cs, bf2f(hv[3]), acc.w);

    int e = rowptr[node];
    const int end = rowptr[node + 1];
    for (; e + 1 < end; e += 2) {
        int s0 = csr_src[e];
        int s1 = csr_src[e + 1];
        float c0 = csr_coef[e];
        float c1 = csr_coef[e + 1];
        s16x4 v0 = h4[(long)s0 * LPN + lane];
        s16x4 v1 = h4[(long)s1 * LPN + lane];
        acc.x = fmaf(c0, bf2f(v0[0]), acc.x);
        acc.y = fmaf(c0, bf2f(v0[1]), acc.y);
        acc.z = fmaf(c0, bf2f(v0[2]), acc.z);
        acc.w = fmaf(c0, bf2f(v0[3]), acc.w);
        acc.x = fmaf(c1, bf2f(v1[0]), acc.x);
        acc.y = fmaf(c1, bf2f(v1[1]), acc.y);
        acc.z = fmaf(c1, bf2f(v1[2]), acc.z);
        acc.w = fmaf(c1, bf2f(v1[3]), acc.w);
    }
    if (e < end) {
        int s0 = csr_src[e];
        float c0 = csr_coef[e];
        s16x4 v0 = h4[(long)s0 * LPN + lane];
        acc.x = fmaf(c0, bf2f(v0[0]), acc.x);
        acc.y = fmaf(c0, bf2f(v0[1]), acc.y);
        acc.z = fmaf(c0, bf2f(v0[2]), acc.z);
        acc.w = fmaf(c0, bf2f(v0[3]), acc.w);
    }
    s16x4 o;
    o[0] = f2bf(fmaxf(acc.x, 0.f));
    o[1] = f2bf(fmaxf(acc.y, 0.f));
    o[2] = f2bf(fmaxf(acc.z, 0.f));
    o[3] = f2bf(fmaxf(acc.w, 0.f));
    ((s16x4*)agg)[(long)node * LPN + lane] = o;
}

// ---- launch -----------------------------------------------------------------
static inline size_t al256(size_t x) { return (x + 255) & ~(size_t)255; }

extern "C" void kernel_launch(void* const* d_in, const int* in_sizes, int n_in,
                              void* d_out, int out_size, void* d_ws, size_t ws_size,
                              hipStream_t stream) {
    const float* x    = (const float*)d_in[0];
    const int*   eraw = (const int*)d_in[1];
    const float* W1   = (const float*)d_in[2];
    const float* b1   = (const float*)d_in[3];
    const float* W2   = (const float*)d_in[4];
    const float* b2   = (const float*)d_in[5];
    const float* Wh   = (const float*)d_in[6];
    const float* bh   = (const float*)d_in[7];
    float* out = (float*)d_out;
    const int n = in_sizes[0] / F_IN;
    const int E = in_sizes[1] / 2;
    const int nb = (n + 255) / 256;

    // ---- workspace layout ----
    char* p = (char*)d_ws;
    int*   flag     = (int*)p;   p += 256;
    float* dinv     = (float*)p; p += al256((size_t)n * 4);
    int*   rowptr   = (int*)p;   p += al256((size_t)(n + 1) * 4);
    int*   bsums    = (int*)p;   p += 4096;
    int*   csr_src  = (int*)p;   p += al256((size_t)E * 4);
    float* csr_coef = (float*)p; p += al256((size_t)E * 4);
    int*   degcur   = (int*)p;   p += al256((size_t)n * 4);
    short* W1t      = (short*)p; p += al256((size_t)HH1 * F_IN * 2);
    short* W2t      = (short*)p; p += al256((size_t)HH2 * HH1 * 2);
    short* Whtp     = (short*)p; p += al256((size_t)64 * HH2 * 2);
    short* bigA     = (short*)p; p += al256((size_t)n * HH1 * 2);   // 12.8 MB
    short* bigB     = (short*)p;                                    // 12.8 MB
    // edges overlay bigA (dead before GEMM1 writes h1)
    int* edges = (int*)bigA;
    const int* srcv = edges;
    const int* dstv = edges + E;
    short* h1   = bigA;
    short* agg1 = bigB;
    short* h2   = bigA;                          // 6.4 MB
    short* agg2 = bigA + (size_t)n * HH2;        // disjoint from h2
    int* deg = degcur;
    int* cursor = degcur;

    dim3 blk(256);
    // graph prep
    detect_kernel<<<1, 256, 0, stream>>>((const unsigned int*)eraw, flag);
    convert_edges<<<(2 * E + 255) / 256, blk, 0, stream>>>(eraw, flag, edges, 2 * E);
    init_deg<<<nb, blk, 0, stream>>>(deg, n);
    count_deg<<<(E + 255) / 256, blk, 0, stream>>>(dstv, deg, E);
    make_dinv<<<nb, blk, 0, stream>>>(deg, dinv, n);
    scan_block<<<nb, blk, 0, stream>>>(deg, rowptr, bsums, n);
    scan_tops<<<1, blk, 0, stream>>>(bsums, nb);
    scan_add<<<nb, blk, 0, stream>>>(rowptr, bsums, cursor, n, E);
    scatter_edges<<<(E + 255) / 256, blk, 0, stream>>>(srcv, dstv, dinv, cursor, csr_src, csr_coef, E);
    // weights -> bf16 transposed
    wtrans<<<(HH1 * F_IN + 255) / 256, blk, 0, stream>>>(W1, W1t, F_IN, HH1, HH1);
    wtrans<<<(HH2 * HH1 + 255) / 256, blk, 0, stream>>>(W2, W2t, HH1, HH2, HH2);
    wtrans<<<(64 * HH2 + 255) / 256, blk, 0, stream>>>(Wh, Whtp, HH2, FOUT, 64);

    const int gblocks = (n + 63) / 64;
    // layer 1: h1 = x @ W1 (bf16 out)
    mfma_gemm<F_IN, HH1, false, false, false><<<gblocks, blk, 0, stream>>>(x, W1t, nullptr, h1, n, HH1);
    agg_csr_bf16<32, 8><<<(n + 7) / 8, blk, 0, stream>>>(h1, rowptr, csr_src, csr_coef, dinv, b1, agg1, n);
    // layer 2: h2 = agg1 @ W2
    mfma_gemm<HH1, HH2, true, false, false><<<gblocks, blk, 0, stream>>>(agg1, W2t, nullptr, h2, n, HH2);
    agg_csr_bf16<16, 16><<<(n + 15) / 16, blk, 0, stream>>>(h2, rowptr, csr_src, csr_coef, dinv, b2, agg2, n);
    // head: out = agg2 @ Wh + bh (fp32 out, masked to 50 cols)
    mfma_gemm<HH2, 64, true, true, true><<<gblocks, blk, 0, stream>>>(agg2, Whtp, bh, out, n, FOUT);
}

// Round 4
// 179.881 us; speedup vs baseline: 10.3837x; 1.0860x over previous
//
#include <hip/hip_runtime.h>

#define F_IN 128
#define HH1 128
#define HH2 64
#define FOUT 50

typedef __attribute__((ext_vector_type(8))) short short8;
typedef __attribute__((ext_vector_type(4))) short s16x4;
typedef __attribute__((ext_vector_type(4))) float f32x4;

__device__ inline short f2bf(float f) {  // RNE fp32->bf16
    union { float f; unsigned u; } v; v.f = f;
    unsigned r = v.u + 0x7fffu + ((v.u >> 16) & 1u);
    return (short)(r >> 16);
}
__device__ inline float bf2f(short s) {
    union { float f; unsigned u; } v; v.u = ((unsigned)(unsigned short)s) << 16;
    return v.f;
}

// ---- edge dtype detection (int64 vs int32) ---------------------------------
__global__ void detect_kernel(const unsigned int* __restrict__ raw, int* __restrict__ flag) {
    __shared__ int nonzero;
    if (threadIdx.x == 0) nonzero = 0;
    __syncthreads();
    if (raw[2 * threadIdx.x + 1] != 0u) atomicOr(&nonzero, 1);
    __syncthreads();
    if (threadIdx.x == 0) *flag = (nonzero ? 0 : 1);  // 1 => int64
}

// ---- fused: convert edges to int2 + count in-degree -------------------------
__global__ void prep_edges(const int* __restrict__ raw, const int* __restrict__ flag,
                           int2* __restrict__ edges, int* __restrict__ deg, int E) {
    int e = blockIdx.x * 256 + threadIdx.x;
    if (e >= E) return;
    int is64 = *flag;
    int s, d;
    if (is64) {
        s = raw[2 * e];
        d = raw[2 * (long)E + 2 * e];
    } else {
        s = raw[e];
        d = raw[E + e];
    }
    edges[e] = make_int2(s, d);
    atomicAdd(&deg[d], 1);
}

// ---- exclusive scan over deg (+ dinv) ---------------------------------------
__global__ void scan_block(const int* __restrict__ deg, int* __restrict__ excl,
                           int* __restrict__ bsums, float* __restrict__ dinv, int n) {
    __shared__ int sh[256];
    int tid = threadIdx.x;
    int gid = blockIdx.x * 256 + tid;
    int v = (gid < n) ? deg[gid] : 0;
    sh[tid] = v;
    __syncthreads();
    for (int off = 1; off < 256; off <<= 1) {
        int t = (tid >= off) ? sh[tid - off] : 0;
        __syncthreads();
        sh[tid] += t;
        __syncthreads();
    }
    if (gid < n) {
        excl[gid] = sh[tid] - v;
        dinv[gid] = rsqrtf((float)v + 1.0f);  // +1 self-loop
    }
    if (tid == 255) bsums[blockIdx.x] = sh[255];
}
__global__ void scan_tops(int* __restrict__ bsums, int nb) {
    __shared__ int sh[256];
    int tid = threadIdx.x;
    int v = (tid < nb) ? bsums[tid] : 0;
    sh[tid] = v;
    __syncthreads();
    for (int off = 1; off < 256; off <<= 1) {
        int t = (tid >= off) ? sh[tid - off] : 0;
        __syncthreads();
        sh[tid] += t;
        __syncthreads();
    }
    if (tid < nb) bsums[tid] = sh[tid] - v;  // exclusive
}
__global__ void scan_add(int* __restrict__ rowptr, const int* __restrict__ bsums,
                         int* __restrict__ cursor, int n, int E) {
    int gid = blockIdx.x * 256 + threadIdx.x;
    if (gid < n) {
        int v = rowptr[gid] + bsums[gid >> 8];
        rowptr[gid] = v;
        cursor[gid] = v;
    }
    if (gid == 0) rowptr[n] = E;
}

// ---- CSR scatter: ONE packed 8B write per edge ------------------------------
__global__ void scatter_pack(const int2* __restrict__ edges, const float* __restrict__ dinv,
                             int* __restrict__ cursor, uint2* __restrict__ csr, int E) {
    int e = blockIdx.x * 256 + threadIdx.x;
    if (e >= E) return;
    int2 sd = edges[e];
    float c = dinv[sd.x] * dinv[sd.y];
    int pos = atomicAdd(&cursor[sd.y], 1);
    csr[pos] = make_uint2((unsigned)sd.x, __float_as_uint(c));
}

// ---- all weights -> bf16 transposed, one kernel -----------------------------
__global__ void wtrans_all(const float* __restrict__ W1, const float* __restrict__ W2,
                           const float* __restrict__ Wh, short* __restrict__ W1t,
                           short* __restrict__ W2t, short* __restrict__ Wht) {
    const int T1 = HH1 * F_IN, T2 = HH2 * HH1, T3 = 64 * HH2;
    int idx = blockIdx.x * 256 + threadIdx.x;
    if (idx < T1) {
        int c = idx / F_IN, k = idx - c * F_IN;
        W1t[idx] = f2bf(W1[(long)k * HH1 + c]);
    } else if (idx < T1 + T2) {
        int i = idx - T1;
        int c = i / HH1, k = i - c * HH1;
        W2t[i] = f2bf(W2[(long)k * HH2 + c]);
    } else if (idx < T1 + T2 + T3) {
        int i = idx - T1 - T2;
        int c = i / HH2, k = i - c * HH2;
        Wht[i] = f2bf((c < FOUT) ? Wh[(long)k * FOUT + c] : 0.f);
    }
}

// ---- MFMA GEMM: Y[M,NC] = X[M,K] @ Wt^T, per-wave 16-row tile ---------------
template <int K, int NC, bool IN_BF16, bool OUT_F32, bool BIAS>
__global__ __launch_bounds__(256) void mfma_gemm(const void* __restrict__ Xv,
                                                 const short* __restrict__ Wt,
                                                 const float* __restrict__ bias,
                                                 void* __restrict__ Yv, int M, int NCOUT) {
    const int tid = threadIdx.x;
    const int wave = tid >> 6;
    const int lane = tid & 63;
    const int l15 = lane & 15;
    const int kg = lane >> 4;
    const int rowbase = blockIdx.x * 64 + wave * 16;
    const int arow = rowbase + l15;
    constexpr int KS = K / 32;

    short8 af[KS];
    if (arow < M) {
        if (IN_BF16) {
            const short* xr = (const short*)Xv + (long)arow * K + kg * 8;
#pragma unroll
            for (int ks = 0; ks < KS; ++ks) af[ks] = *(const short8*)(xr + ks * 32);
        } else {
            const float* xr = (const float*)Xv + (long)arow * K + kg * 8;
#pragma unroll
            for (int ks = 0; ks < KS; ++ks) {
                float4 f0 = *(const float4*)(xr + ks * 32);
                float4 f1 = *(const float4*)(xr + ks * 32 + 4);
                short8 a;
                a[0] = f2bf(f0.x); a[1] = f2bf(f0.y); a[2] = f2bf(f0.z); a[3] = f2bf(f0.w);
                a[4] = f2bf(f1.x); a[5] = f2bf(f1.y); a[6] = f2bf(f1.z); a[7] = f2bf(f1.w);
                af[ks] = a;
            }
        }
    } else {
#pragma unroll
        for (int ks = 0; ks < KS; ++ks) af[ks] = (short8)0;
    }

    const int crowb = rowbase + kg * 4;
#pragma unroll
    for (int ct = 0; ct < NC / 16; ++ct) {
        const int col = ct * 16 + l15;
        const short* wr = Wt + (long)col * K + kg * 8;
        f32x4 acc = {0.f, 0.f, 0.f, 0.f};
#pragma unroll
        for (int ks = 0; ks < KS; ++ks) {
            short8 bf = *(const short8*)(wr + ks * 32);
            acc = __builtin_amdgcn_mfma_f32_16x16x32_bf16(af[ks], bf, acc, 0, 0, 0);
        }
        if (OUT_F32) {
            float* Y = (float*)Yv;
            float bv = BIAS ? bias[col] : 0.f;
#pragma unroll
            for (int j = 0; j < 4; ++j) {
                int r = crowb + j;
                if (r < M && col < NCOUT) Y[(long)r * NCOUT + col] = acc[j] + bv;
            }
        } else {
            short* Y = (short*)Yv;
#pragma unroll
            for (int j = 0; j < 4; ++j) {
                int r = crowb + j;
                if (r < M) Y[(long)r * NC + col] = f2bf(acc[j]);
            }
        }
    }
}

// ---- CSR aggregation, bf16 features, packed edges, 4-wide ILP ---------------
// agg[i] = relu(bias + dinv[i]^2*h[i] + sum_e coef*h[src]) -> bf16
template <int LPN, int NPB>
__global__ __launch_bounds__(256) void agg_csr_bf16(const short* __restrict__ h,
                                                    const int* __restrict__ rowptr,
                                                    const uint2* __restrict__ csr,
                                                    const float* __restrict__ dinv,
                                                    const float* __restrict__ bias,
                                                    short* __restrict__ agg, int n) {
    const int tid = threadIdx.x;
    const int node = blockIdx.x * NPB + tid / LPN;
    const int lane = tid % LPN;
    if (node >= n) return;
    const s16x4* __restrict__ h4 = (const s16x4*)h;

    float4 acc = ((const float4*)bias)[lane];
    float di = dinv[node];
    float cs = di * di;
    s16x4 hv = h4[(long)node * LPN + lane];
    acc.x = fmaf(cs, bf2f(hv[0]), acc.x);
    acc.y = fmaf(cs, bf2f(hv[1]), acc.y);
    acc.z = fmaf(cs, bf2f(hv[2]), acc.z);
    acc.w = fmaf(cs, bf2f(hv[3]), acc.w);

    int e = rowptr[node];
    const int end = rowptr[node + 1];
    for (; e + 3 < end; e += 4) {
        uint2 p0 = csr[e];
        uint2 p1 = csr[e + 1];
        uint2 p2 = csr[e + 2];
        uint2 p3 = csr[e + 3];
        s16x4 v0 = h4[(long)p0.x * LPN + lane];
        s16x4 v1 = h4[(long)p1.x * LPN + lane];
        s16x4 v2 = h4[(long)p2.x * LPN + lane];
        s16x4 v3 = h4[(long)p3.x * LPN + lane];
        float c0 = __uint_as_float(p0.y);
        float c1 = __uint_as_float(p1.y);
        float c2 = __uint_as_float(p2.y);
        float c3 = __uint_as_float(p3.y);
        acc.x = fmaf(c0, bf2f(v0[0]), acc.x);
        acc.y = fmaf(c0, bf2f(v0[1]), acc.y);
        acc.z = fmaf(c0, bf2f(v0[2]), acc.z);
        acc.w = fmaf(c0, bf2f(v0[3]), acc.w);
        acc.x = fmaf(c1, bf2f(v1[0]), acc.x);
        acc.y = fmaf(c1, bf2f(v1[1]), acc.y);
        acc.z = fmaf(c1, bf2f(v1[2]), acc.z);
        acc.w = fmaf(c1, bf2f(v1[3]), acc.w);
        acc.x = fmaf(c2, bf2f(v2[0]), acc.x);
        acc.y = fmaf(c2, bf2f(v2[1]), acc.y);
        acc.z = fmaf(c2, bf2f(v2[2]), acc.z);
        acc.w = fmaf(c2, bf2f(v2[3]), acc.w);
        acc.x = fmaf(c3, bf2f(v3[0]), acc.x);
        acc.y = fmaf(c3, bf2f(v3[1]), acc.y);
        acc.z = fmaf(c3, bf2f(v3[2]), acc.z);
        acc.w = fmaf(c3, bf2f(v3[3]), acc.w);
    }
    for (; e < end; ++e) {
        uint2 p0 = csr[e];
        float c0 = __uint_as_float(p0.y);
        s16x4 v0 = h4[(long)p0.x * LPN + lane];
        acc.x = fmaf(c0, bf2f(v0[0]), acc.x);
        acc.y = fmaf(c0, bf2f(v0[1]), acc.y);
        acc.z = fmaf(c0, bf2f(v0[2]), acc.z);
        acc.w = fmaf(c0, bf2f(v0[3]), acc.w);
    }
    s16x4 o;
    o[0] = f2bf(fmaxf(acc.x, 0.f));
    o[1] = f2bf(fmaxf(acc.y, 0.f));
    o[2] = f2bf(fmaxf(acc.z, 0.f));
    o[3] = f2bf(fmaxf(acc.w, 0.f));
    ((s16x4*)agg)[(long)node * LPN + lane] = o;
}

// ---- launch -----------------------------------------------------------------
static inline size_t al256(size_t x) { return (x + 255) & ~(size_t)255; }

extern "C" void kernel_launch(void* const* d_in, const int* in_sizes, int n_in,
                              void* d_out, int out_size, void* d_ws, size_t ws_size,
                              hipStream_t stream) {
    const float* x    = (const float*)d_in[0];
    const int*   eraw = (const int*)d_in[1];
    const float* W1   = (const float*)d_in[2];
    const float* b1   = (const float*)d_in[3];
    const float* W2   = (const float*)d_in[4];
    const float* b2   = (const float*)d_in[5];
    const float* Wh   = (const float*)d_in[6];
    const float* bh   = (const float*)d_in[7];
    float* out = (float*)d_out;
    const int n = in_sizes[0] / F_IN;
    const int E = in_sizes[1] / 2;
    const int nb = (n + 255) / 256;

    // ---- workspace layout ----
    char* p = (char*)d_ws;
    int*   flag     = (int*)p;   p += 256;
    float* dinv     = (float*)p; p += al256((size_t)n * 4);
    int*   rowptr   = (int*)p;   p += al256((size_t)(n + 1) * 4);
    int*   bsums    = (int*)p;   p += 4096;
    uint2* csr      = (uint2*)p; p += al256((size_t)E * 8);
    int*   degcur   = (int*)p;   p += al256((size_t)n * 4);   // deg, then cursor
    short* W1t      = (short*)p; p += al256((size_t)HH1 * F_IN * 2);
    short* W2t      = (short*)p; p += al256((size_t)HH2 * HH1 * 2);
    short* Whtp     = (short*)p; p += al256((size_t)64 * HH2 * 2);
    short* bigA     = (short*)p; p += al256((size_t)n * HH1 * 2);   // 12.8 MB
    short* bigB     = (short*)p;                                    // 12.8 MB
    // int2 edge list overlays bigA (dead before GEMM1 writes h1)
    int2* edges = (int2*)bigA;
    short* h1   = bigA;
    short* agg1 = bigB;
    short* h2   = bigA;                          // 6.4 MB
    short* agg2 = bigA + (size_t)n * HH2;        // disjoint from h2
    int* deg = degcur;
    int* cursor = degcur;

    dim3 blk(256);
    // graph prep
    detect_kernel<<<1, 256, 0, stream>>>((const unsigned int*)eraw, flag);
    hipMemsetAsync(deg, 0, (size_t)n * sizeof(int), stream);
    prep_edges<<<(E + 255) / 256, blk, 0, stream>>>(eraw, flag, edges, deg, E);
    scan_block<<<nb, blk, 0, stream>>>(deg, rowptr, bsums, dinv, n);
    scan_tops<<<1, blk, 0, stream>>>(bsums, nb);
    scan_add<<<nb, blk, 0, stream>>>(rowptr, bsums, cursor, n, E);
    scatter_pack<<<(E + 255) / 256, blk, 0, stream>>>(edges, dinv, cursor, csr, E);
    wtrans_all<<<(HH1 * F_IN + HH2 * HH1 + 64 * HH2 + 255) / 256, blk, 0, stream>>>(
        W1, W2, Wh, W1t, W2t, Whtp);

    const int gblocks = (n + 63) / 64;
    // layer 1: h1 = x @ W1 (bf16 out)
    mfma_gemm<F_IN, HH1, false, false, false><<<gblocks, blk, 0, stream>>>(x, W1t, nullptr, h1, n, HH1);
    agg_csr_bf16<32, 8><<<(n + 7) / 8, blk, 0, stream>>>(h1, rowptr, csr, dinv, b1, agg1, n);
    // layer 2: h2 = agg1 @ W2
    mfma_gemm<HH1, HH2, true, false, false><<<gblocks, blk, 0, stream>>>(agg1, W2t, nullptr, h2, n, HH2);
    agg_csr_bf16<16, 16><<<(n + 15) / 16, blk, 0, stream>>>(h2, rowptr, csr, dinv, b2, agg2, n);
    // head: out = agg2 @ Wh + bh (fp32 out, masked to 50 cols)
    mfma_gemm<HH2, 64, true, true, true><<<gblocks, blk, 0, stream>>>(agg2, Whtp, bh, out, n, FOUT);
}

// Round 5
// 176.893 us; speedup vs baseline: 10.5591x; 1.0169x over previous
//
#include <hip/hip_runtime.h>

#define F_IN 128
#define HH1 128
#define HH2 64
#define FOUT 50

typedef __attribute__((ext_vector_type(8))) short short8;
typedef __attribute__((ext_vector_type(4))) short s16x4;
typedef __attribute__((ext_vector_type(4))) float f32x4;

__device__ inline short f2bf(float f) {  // RNE fp32->bf16
    union { float f; unsigned u; } v; v.f = f;
    unsigned r = v.u + 0x7fffu + ((v.u >> 16) & 1u);
    return (short)(r >> 16);
}
__device__ inline float bf2f(short s) {
    union { float f; unsigned u; } v; v.u = ((unsigned)(unsigned short)s) << 16;
    return v.f;
}

// ---- zero int buffer (grid-strided int4) ------------------------------------
__global__ void zero_ints(int4* __restrict__ p, int n4) {
    int i = blockIdx.x * 256 + threadIdx.x;
    int stride = gridDim.x * 256;
    for (; i < n4; i += stride) p[i] = make_int4(0, 0, 0, 0);
}

// ---- edge dtype detection (int64 vs int32) ---------------------------------
__global__ void detect_kernel(const unsigned int* __restrict__ raw, int* __restrict__ flag) {
    __shared__ int nonzero;
    if (threadIdx.x == 0) nonzero = 0;
    __syncthreads();
    if (raw[2 * threadIdx.x + 1] != 0u) atomicOr(&nonzero, 1);
    __syncthreads();
    if (threadIdx.x == 0) *flag = (nonzero ? 0 : 1);  // 1 => int64
}

// ---- fused: convert edges to int2 + count in-degree -------------------------
__global__ void prep_edges(const int* __restrict__ raw, const int* __restrict__ flag,
                           int2* __restrict__ edges, int* __restrict__ deg, int E) {
    int e = blockIdx.x * 256 + threadIdx.x;
    if (e >= E) return;
    int is64 = *flag;
    int s, d;
    if (is64) {
        s = raw[2 * e];
        d = raw[2 * (long)E + 2 * e];
    } else {
        s = raw[e];
        d = raw[E + e];
    }
    edges[e] = make_int2(s, d);
    atomicAdd(&deg[d], 1);
}

// ---- exclusive scan over deg (+ dinv) ---------------------------------------
__global__ void scan_block(const int* __restrict__ deg, int* __restrict__ excl,
                           int* __restrict__ bsums, float* __restrict__ dinv, int n) {
    __shared__ int sh[256];
    int tid = threadIdx.x;
    int gid = blockIdx.x * 256 + tid;
    int v = (gid < n) ? deg[gid] : 0;
    sh[tid] = v;
    __syncthreads();
    for (int off = 1; off < 256; off <<= 1) {
        int t = (tid >= off) ? sh[tid - off] : 0;
        __syncthreads();
        sh[tid] += t;
        __syncthreads();
    }
    if (gid < n) {
        excl[gid] = sh[tid] - v;
        dinv[gid] = rsqrtf((float)v + 1.0f);  // +1 self-loop
    }
    if (tid == 255) bsums[blockIdx.x] = sh[255];
}
__global__ void scan_tops(int* __restrict__ bsums, int nb) {
    __shared__ int sh[256];
    int tid = threadIdx.x;
    int v = (tid < nb) ? bsums[tid] : 0;
    sh[tid] = v;
    __syncthreads();
    for (int off = 1; off < 256; off <<= 1) {
        int t = (tid >= off) ? sh[tid - off] : 0;
        __syncthreads();
        sh[tid] += t;
        __syncthreads();
    }
    if (tid < nb) bsums[tid] = sh[tid] - v;  // exclusive
}
__global__ void scan_add(int* __restrict__ rowptr, const int* __restrict__ bsums,
                         int* __restrict__ cursor, int n, int E) {
    int gid = blockIdx.x * 256 + threadIdx.x;
    if (gid < n) {
        int v = rowptr[gid] + bsums[gid >> 8];
        rowptr[gid] = v;
        cursor[gid] = v;
    }
    if (gid == 0) rowptr[n] = E;
}

// ---- CSR scatter: ONE packed 8B write per edge ------------------------------
__global__ void scatter_pack(const int2* __restrict__ edges, const float* __restrict__ dinv,
                             int* __restrict__ cursor, uint2* __restrict__ csr, int E) {
    int e = blockIdx.x * 256 + threadIdx.x;
    if (e >= E) return;
    int2 sd = edges[e];
    float c = dinv[sd.x] * dinv[sd.y];
    int pos = atomicAdd(&cursor[sd.y], 1);
    csr[pos] = make_uint2((unsigned)sd.x, __float_as_uint(c));
}

// ---- all weights -> bf16 transposed, one kernel -----------------------------
__global__ void wtrans_all(const float* __restrict__ W1, const float* __restrict__ W2,
                           const float* __restrict__ Wh, short* __restrict__ W1t,
                           short* __restrict__ W2t, short* __restrict__ Wht) {
    const int T1 = HH1 * F_IN, T2 = HH2 * HH1, T3 = 64 * HH2;
    int idx = blockIdx.x * 256 + threadIdx.x;
    if (idx < T1) {
        int c = idx / F_IN, k = idx - c * F_IN;
        W1t[idx] = f2bf(W1[(long)k * HH1 + c]);
    } else if (idx < T1 + T2) {
        int i = idx - T1;
        int c = i / HH1, k = i - c * HH1;
        W2t[i] = f2bf(W2[(long)k * HH2 + c]);
    } else if (idx < T1 + T2 + T3) {
        int i = idx - T1 - T2;
        int c = i / HH2, k = i - c * HH2;
        Wht[i] = f2bf((c < FOUT) ? Wh[(long)k * FOUT + c] : 0.f);
    }
}

// ---- MFMA GEMM: Y[M,NC] = X[M,K] @ Wt^T, per-wave 16-row tile ---------------
template <int K, int NC, bool IN_BF16, bool OUT_F32, bool BIAS>
__global__ __launch_bounds__(256) void mfma_gemm(const void* __restrict__ Xv,
                                                 const short* __restrict__ Wt,
                                                 const float* __restrict__ bias,
                                                 void* __restrict__ Yv, int M, int NCOUT) {
    const int tid = threadIdx.x;
    const int wave = tid >> 6;
    const int lane = tid & 63;
    const int l15 = lane & 15;
    const int kg = lane >> 4;
    const int rowbase = blockIdx.x * 64 + wave * 16;
    const int arow = rowbase + l15;
    constexpr int KS = K / 32;

    short8 af[KS];
    if (arow < M) {
        if (IN_BF16) {
            const short* xr = (const short*)Xv + (long)arow * K + kg * 8;
#pragma unroll
            for (int ks = 0; ks < KS; ++ks) af[ks] = *(const short8*)(xr + ks * 32);
        } else {
            const float* xr = (const float*)Xv + (long)arow * K + kg * 8;
#pragma unroll
            for (int ks = 0; ks < KS; ++ks) {
                float4 f0 = *(const float4*)(xr + ks * 32);
                float4 f1 = *(const float4*)(xr + ks * 32 + 4);
                short8 a;
                a[0] = f2bf(f0.x); a[1] = f2bf(f0.y); a[2] = f2bf(f0.z); a[3] = f2bf(f0.w);
                a[4] = f2bf(f1.x); a[5] = f2bf(f1.y); a[6] = f2bf(f1.z); a[7] = f2bf(f1.w);
                af[ks] = a;
            }
        }
    } else {
#pragma unroll
        for (int ks = 0; ks < KS; ++ks) af[ks] = (short8)0;
    }

    const int crowb = rowbase + kg * 4;
#pragma unroll
    for (int ct = 0; ct < NC / 16; ++ct) {
        const int col = ct * 16 + l15;
        const short* wr = Wt + (long)col * K + kg * 8;
        f32x4 acc = {0.f, 0.f, 0.f, 0.f};
#pragma unroll
        for (int ks = 0; ks < KS; ++ks) {
            short8 bf = *(const short8*)(wr + ks * 32);
            acc = __builtin_amdgcn_mfma_f32_16x16x32_bf16(af[ks], bf, acc, 0, 0, 0);
        }
        if (OUT_F32) {
            float* Y = (float*)Yv;
            float bv = BIAS ? bias[col] : 0.f;
#pragma unroll
            for (int j = 0; j < 4; ++j) {
                int r = crowb + j;
                if (r < M && col < NCOUT) Y[(long)r * NCOUT + col] = acc[j] + bv;
            }
        } else {
            short* Y = (short*)Yv;
#pragma unroll
            for (int j = 0; j < 4; ++j) {
                int r = crowb + j;
                if (r < M) Y[(long)r * NC + col] = f2bf(acc[j]);
            }
        }
    }
}

// ---- CSR aggregation, bf16 features, packed edges, 4-wide ILP ---------------
// agg[i] = relu(bias + dinv[i]^2*h[i] + sum_e coef*h[src]) -> bf16
template <int LPN, int NPB>
__global__ __launch_bounds__(256) void agg_csr_bf16(const short* __restrict__ h,
                                                    const int* __restrict__ rowptr,
                                                    const uint2* __restrict__ csr,
                                                    const float* __restrict__ dinv,
                                                    const float* __restrict__ bias,
                                                    short* __restrict__ agg, int n) {
    const int tid = threadIdx.x;
    const int node = blockIdx.x * NPB + tid / LPN;
    const int lane = tid % LPN;
    if (node >= n) return;
    const s16x4* __restrict__ h4 = (const s16x4*)h;

    float4 acc = ((const float4*)bias)[lane];
    float di = dinv[node];
    float cs = di * di;
    s16x4 hv = h4[(long)node * LPN + lane];
    acc.x = fmaf(cs, bf2f(hv[0]), acc.x);
    acc.y = fmaf(cs, bf2f(hv[1]), acc.y);
    acc.z = fmaf(cs, bf2f(hv[2]), acc.z);
    acc.w = fmaf(cs, bf2f(hv[3]), acc.w);

    int e = rowptr[node];
    const int end = rowptr[node + 1];
    for (; e + 3 < end; e += 4) {
        uint2 p0 = csr[e];
        uint2 p1 = csr[e + 1];
        uint2 p2 = csr[e + 2];
        uint2 p3 = csr[e + 3];
        s16x4 v0 = h4[(long)p0.x * LPN + lane];
        s16x4 v1 = h4[(long)p1.x * LPN + lane];
        s16x4 v2 = h4[(long)p2.x * LPN + lane];
        s16x4 v3 = h4[(long)p3.x * LPN + lane];
        float c0 = __uint_as_float(p0.y);
        float c1 = __uint_as_float(p1.y);
        float c2 = __uint_as_float(p2.y);
        float c3 = __uint_as_float(p3.y);
        acc.x = fmaf(c0, bf2f(v0[0]), acc.x);
        acc.y = fmaf(c0, bf2f(v0[1]), acc.y);
        acc.z = fmaf(c0, bf2f(v0[2]), acc.z);
        acc.w = fmaf(c0, bf2f(v0[3]), acc.w);
        acc.x = fmaf(c1, bf2f(v1[0]), acc.x);
        acc.y = fmaf(c1, bf2f(v1[1]), acc.y);
        acc.z = fmaf(c1, bf2f(v1[2]), acc.z);
        acc.w = fmaf(c1, bf2f(v1[3]), acc.w);
        acc.x = fmaf(c2, bf2f(v2[0]), acc.x);
        acc.y = fmaf(c2, bf2f(v2[1]), acc.y);
        acc.z = fmaf(c2, bf2f(v2[2]), acc.z);
        acc.w = fmaf(c2, bf2f(v2[3]), acc.w);
        acc.x = fmaf(c3, bf2f(v3[0]), acc.x);
        acc.y = fmaf(c3, bf2f(v3[1]), acc.y);
        acc.z = fmaf(c3, bf2f(v3[2]), acc.z);
        acc.w = fmaf(c3, bf2f(v3[3]), acc.w);
    }
    for (; e < end; ++e) {
        uint2 p0 = csr[e];
        float c0 = __uint_as_float(p0.y);
        s16x4 v0 = h4[(long)p0.x * LPN + lane];
        acc.x = fmaf(c0, bf2f(v0[0]), acc.x);
        acc.y = fmaf(c0, bf2f(v0[1]), acc.y);
        acc.z = fmaf(c0, bf2f(v0[2]), acc.z);
        acc.w = fmaf(c0, bf2f(v0[3]), acc.w);
    }
    s16x4 o;
    o[0] = f2bf(fmaxf(acc.x, 0.f));
    o[1] = f2bf(fmaxf(acc.y, 0.f));
    o[2] = f2bf(fmaxf(acc.z, 0.f));
    o[3] = f2bf(fmaxf(acc.w, 0.f));
    ((s16x4*)agg)[(long)node * LPN + lane] = o;
}

// ---- launch -----------------------------------------------------------------
static inline size_t al256(size_t x) { return (x + 255) & ~(size_t)255; }

extern "C" void kernel_launch(void* const* d_in, const int* in_sizes, int n_in,
                              void* d_out, int out_size, void* d_ws, size_t ws_size,
                              hipStream_t stream) {
    const float* x    = (const float*)d_in[0];
    const int*   eraw = (const int*)d_in[1];
    const float* W1   = (const float*)d_in[2];
    const float* b1   = (const float*)d_in[3];
    const float* W2   = (const float*)d_in[4];
    const float* b2   = (const float*)d_in[5];
    const float* Wh   = (const float*)d_in[6];
    const float* bh   = (const float*)d_in[7];
    float* out = (float*)d_out;
    const int n = in_sizes[0] / F_IN;
    const int E = in_sizes[1] / 2;
    const int nb = (n + 255) / 256;

    // ---- workspace layout ----
    char* p = (char*)d_ws;
    int*   flag     = (int*)p;   p += 256;
    float* dinv     = (float*)p; p += al256((size_t)n * 4);
    int*   rowptr   = (int*)p;   p += al256((size_t)(n + 1) * 4);
    int*   bsums    = (int*)p;   p += 4096;
    uint2* csr      = (uint2*)p; p += al256((size_t)E * 8);
    int*   degcur   = (int*)p;   p += al256((size_t)(n + 4) * 4);   // deg, then cursor
    short* W1t      = (short*)p; p += al256((size_t)HH1 * F_IN * 2);
    short* W2t      = (short*)p; p += al256((size_t)HH2 * HH1 * 2);
    short* Whtp     = (short*)p; p += al256((size_t)64 * HH2 * 2);
    short* bigA     = (short*)p; p += al256((size_t)n * HH1 * 2);   // 12.8 MB
    short* bigB     = (short*)p;                                    // 12.8 MB
    // int2 edge list overlays bigA (dead before GEMM1 writes h1)
    int2* edges = (int2*)bigA;
    short* h1   = bigA;
    short* agg1 = bigB;
    short* h2   = bigA;                          // 6.4 MB
    short* agg2 = bigA + (size_t)n * HH2;        // disjoint from h2
    int* deg = degcur;
    int* cursor = degcur;

    dim3 blk(256);
    // graph prep
    detect_kernel<<<1, 256, 0, stream>>>((const unsigned int*)eraw, flag);
    zero_ints<<<64, blk, 0, stream>>>((int4*)deg, (n + 3) / 4);
    prep_edges<<<(E + 255) / 256, blk, 0, stream>>>(eraw, flag, edges, deg, E);
    scan_block<<<nb, blk, 0, stream>>>(deg, rowptr, bsums, dinv, n);
    scan_tops<<<1, blk, 0, stream>>>(bsums, nb);
    scan_add<<<nb, blk, 0, stream>>>(rowptr, bsums, cursor, n, E);
    scatter_pack<<<(E + 255) / 256, blk, 0, stream>>>(edges, dinv, cursor, csr, E);
    wtrans_all<<<(HH1 * F_IN + HH2 * HH1 + 64 * HH2 + 255) / 256, blk, 0, stream>>>(
        W1, W2, Wh, W1t, W2t, Whtp);

    const int gblocks = (n + 63) / 64;
    // layer 1: h1 = x @ W1 (bf16 out)
    mfma_gemm<F_IN, HH1, false, false, false><<<gblocks, blk, 0, stream>>>(x, W1t, nullptr, h1, n, HH1);
    agg_csr_bf16<32, 8><<<(n + 7) / 8, blk, 0, stream>>>(h1, rowptr, csr, dinv, b1, agg1, n);
    // layer 2: h2 = agg1 @ W2
    mfma_gemm<HH1, HH2, true, false, false><<<gblocks, blk, 0, stream>>>(agg1, W2t, nullptr, h2, n, HH2);
    agg_csr_bf16<16, 16><<<(n + 15) / 16, blk, 0, stream>>>(h2, rowptr, csr, dinv, b2, agg2, n);
    // head: out = agg2 @ Wh + bh (fp32 out, masked to 50 cols)
    mfma_gemm<HH2, 64, true, true, true><<<gblocks, blk, 0, stream>>>(agg2, Whtp, bh, out, n, FOUT);
}